// Round 2
// baseline (304.289 us; speedup 1.0000x reference)
//
#include <hip/hip_runtime.h>

typedef _Float16 half8 __attribute__((ext_vector_type(8)));
typedef _Float16 half4 __attribute__((ext_vector_type(4)));
typedef float floatx4 __attribute__((ext_vector_type(4)));

#define NROW 196        // image tokens after slicing [:,1:]
#define NCOL 64         // text tokens after slicing [:,1:]
#define DIM  768
#define BK   64
#define IMG4 (64 * 196 * 192)   // float4 groups in sliced image
#define TXT4 (64 * 64 * 192)

// async 16B/lane DMA: lane i -> ldsbase + i*16. Global addr is per-lane.
__device__ __forceinline__ void gl_lds16(const _Float16* g, _Float16* l) {
  __builtin_amdgcn_global_load_lds(
      (const __attribute__((address_space(1))) unsigned int*)g,
      (__attribute__((address_space(3))) unsigned int*)l,
      16, 0, 0);
}

// ---------------- f32 -> f16 slice+convert (image + text in one launch) ----
__global__ __launch_bounds__(256) void convert_both(const float* __restrict__ img,
                                                    const float* __restrict__ txt,
                                                    _Float16* __restrict__ imgh,
                                                    _Float16* __restrict__ txth) {
  int idx = blockIdx.x * 256 + threadIdx.x;
  const float* src;
  _Float16* dst;
  int local, i;
  if (idx < IMG4) {
    local = idx;
    int row = local / 192;
    i = row / 196;
    src = img; dst = imgh;
  } else {
    local = idx - IMG4;
    if (local >= TXT4) return;
    int row = local / 192;
    i = row / 64;
    src = txt; dst = txth;
  }
  size_t e = (size_t)local * 4;
  const floatx4 v = *(const floatx4*)(src + e + (size_t)768 * (i + 1));
  half4 h;
  h[0] = (_Float16)v[0]; h[1] = (_Float16)v[1];
  h[2] = (_Float16)v[2]; h[3] = (_Float16)v[3];
  *(half4*)(dst + e) = h;
}

// ---------------- per-(i,j) similarity tile + reductions ----------------
// LDS layout (no padding; XOR-swizzled within each 128B row):
//   A: rows 0..207, row r at SH + r*64 halfs; 16B-granule position p holds
//      global granule g = p ^ (r&7)           (26624 B = issues 0..25)
//   B: rows 0..63 at SH + 13312 halfs, same swizzle (8192 B = issues 26..33)
__global__ __launch_bounds__(256, 4) void sim_kernel(const _Float16* __restrict__ imgh,
                                                     const _Float16* __restrict__ txth,
                                                     const int* __restrict__ pm,
                                                     const float* __restrict__ logit_scale,
                                                     float* __restrict__ lpi,
                                                     float* __restrict__ lpt) {
  __shared__ _Float16 SH[34 * 512];      // 34816 B
  __shared__ float colmaxLDS[4][64];
  __shared__ float wsumLDS[4];

  const int j = blockIdx.x, i = blockIdx.y;
  const int tid = threadIdx.x;
  const int wave = tid >> 6, lane = tid & 63;
  const int quad = lane >> 4, r16 = lane & 15;
  const int NT = (wave == 0) ? 4 : 3;    // row tiles per wave: {w, w+4, w+8, (w+12)}
  const int nIss = (wave < 2) ? 9 : 8;   // staging issues per wave (34 total)

  const _Float16* Abase = imgh + (size_t)i * NROW * DIM;
  const _Float16* Bbase = txth + (size_t)j * NCOL * DIM;

  // precompute per-lane DMA source addresses (loop-invariant except +BK per kk)
  const _Float16* gsrc[9];
#pragma unroll
  for (int k = 0; k < 9; ++k) {
    int it = wave + 4 * k;
    int slot = it * 64 + lane;
    if (slot < 1664) {                   // A: 208 rows x 8 granules
      int r = slot >> 3;
      if (r > 195) r = 195;              // pad rows duplicate row 195 (ignored later)
      int p = slot & 7;
      int g = p ^ (r & 7);
      gsrc[k] = Abase + r * DIM + g * 8;
    } else {                             // B: 64 rows x 8 granules
      int sb = slot - 1664;
      int r = sb >> 3, p = sb & 7;
      int g = p ^ (r & 7);
      gsrc[k] = Bbase + r * DIM + g * 8;
    }
  }

  floatx4 acc[4][4];
#pragma unroll
  for (int t = 0; t < 4; ++t)
#pragma unroll
    for (int ct = 0; ct < 4; ++ct)
      acc[t][ct] = (floatx4){0.f, 0.f, 0.f, 0.f};

  for (int kk = 0; kk < 12; ++kk) {
    // ---- async stage A+B for this K-chunk ----
#pragma unroll
    for (int k = 0; k < 9; ++k) {
      if (k < nIss) {
        gl_lds16(gsrc[k], &SH[(wave + 4 * k) * 512]);
        gsrc[k] += BK;
      }
    }
    __syncthreads();   // drains vmcnt -> DMA visible

    // ---- MFMA on the staged chunk ----
#pragma unroll
    for (int ks = 0; ks < BK; ks += 32) {
      const int p8 = (((ks >> 3) + quad) ^ (r16 & 7)) * 8;   // swizzled granule
      half8 bfrag[4];
#pragma unroll
      for (int ct = 0; ct < 4; ++ct)
        bfrag[ct] = *(const half8*)(&SH[13312 + (ct * 16 + r16) * 64 + p8]);
#pragma unroll
      for (int t = 0; t < 4; ++t) {
        if (t < NT) {
          int rt = wave + 4 * t;
          half8 afrag = *(const half8*)(&SH[(rt * 16 + r16) * 64 + p8]);
#pragma unroll
          for (int ct = 0; ct < 4; ++ct)
            acc[t][ct] = __builtin_amdgcn_mfma_f32_16x16x32_f16(afrag, bfrag[ct], acc[t][ct], 0, 0, 0);
        }
      }
    }
    __syncthreads();
  }

  // ---------------- epilogue ----------------
  const float s = logit_scale[0];
  // reference broadcasts pm over i (NOT j): col m masked iff pm[i, m+1] != 0
  bool maskc[4];
#pragma unroll
  for (int ct = 0; ct < 4; ++ct)
    maskc[ct] = pm[i * 65 + 1 + ct * 16 + r16] != 0;

  // ---- logits_per_image: mean_n of max over valid m ----
  float rowsum = 0.f;
#pragma unroll
  for (int t = 0; t < 4; ++t) {
    if (t < NT) {
      int rt = wave + 4 * t;
#pragma unroll
      for (int r = 0; r < 4; ++r) {
        int row = rt * 16 + quad * 4 + r;   // C/D: row = quad*4 + reg
        float rm = -__builtin_inff();
#pragma unroll
        for (int ct = 0; ct < 4; ++ct) {
          float v = acc[t][ct][r] * s;
          rm = fmaxf(rm, maskc[ct] ? -__builtin_inff() : v);
        }
#pragma unroll
        for (int off = 1; off < 16; off <<= 1)
          rm = fmaxf(rm, __shfl_xor(rm, off, 64));
        if (row < NROW) rowsum += rm;       // counted by all 16 r16 lanes
      }
    }
  }
#pragma unroll
  for (int off = 1; off < 64; off <<= 1) rowsum += __shfl_xor(rowsum, off, 64);
  if (lane == 0) wsumLDS[wave] = rowsum;

  // ---- logits_per_text: masked mean over m of max over n (pad rows excluded) ----
  float cm[4];
#pragma unroll
  for (int ct = 0; ct < 4; ++ct) {
    cm[ct] = -__builtin_inff();
#pragma unroll
    for (int t = 0; t < 4; ++t) {
      if (t < NT) {
        int rt = wave + 4 * t;
#pragma unroll
        for (int r = 0; r < 4; ++r) {
          int row = rt * 16 + quad * 4 + r;
          if (row < NROW) cm[ct] = fmaxf(cm[ct], acc[t][ct][r] * s);
        }
      }
    }
    cm[ct] = fmaxf(cm[ct], __shfl_xor(cm[ct], 16, 64));
    cm[ct] = fmaxf(cm[ct], __shfl_xor(cm[ct], 32, 64));
  }
  if (lane < 16) {
#pragma unroll
    for (int ct = 0; ct < 4; ++ct) colmaxLDS[wave][ct * 16 + lane] = cm[ct];
  }
  __syncthreads();

  if (tid == 0) {
    float total = wsumLDS[0] + wsumLDS[1] + wsumLDS[2] + wsumLDS[3];
    lpi[i * 64 + j] = total / (16.f * (float)NROW);
  }
  if (tid < 64) {   // exactly wave 0
    int col = tid;
    float v = fmaxf(fmaxf(colmaxLDS[0][col], colmaxLDS[1][col]),
                    fmaxf(colmaxLDS[2][col], colmaxLDS[3][col]));
    bool valid = pm[i * 65 + 1 + col] == 0;
    float contrib = valid ? v : 0.f;
    float cntv = valid ? 1.f : 0.f;
#pragma unroll
    for (int off = 1; off < 64; off <<= 1) {
      contrib += __shfl_xor(contrib, off, 64);
      cntv += __shfl_xor(cntv, off, 64);
    }
    if (tid == 0) lpt[i * 64 + j] = contrib / cntv;
  }
}

// ---------------- CE losses + targets ----------------
// out layout: [0] loss | [1..4097) lpi | [4097..8193) lpt | [8193..8257) targets
__global__ __launch_bounds__(64) void ce_kernel(float* __restrict__ out) {
  const int t = threadIdx.x;  // 1 wave, thread t = row t
  const float* lpi = out + 1;
  const float* lpt = out + 1 + 4096;

  float mx = -__builtin_inff();
  for (int jj = 0; jj < 64; ++jj) mx = fmaxf(mx, lpi[t * 64 + jj]);
  float se = 0.f;
  for (int jj = 0; jj < 64; ++jj) se += __expf(lpi[t * 64 + jj] - mx);
  float ci = (mx + __logf(se)) - lpi[t * 64 + t];

  float mx2 = -__builtin_inff();
  for (int jj = 0; jj < 64; ++jj) mx2 = fmaxf(mx2, lpt[t * 64 + jj]);
  float se2 = 0.f;
  for (int jj = 0; jj < 64; ++jj) se2 += __expf(lpt[t * 64 + jj] - mx2);
  float ct_ = (mx2 + __logf(se2)) - lpt[t * 64 + t];

  float v = ci + ct_;
#pragma unroll
  for (int off = 1; off < 64; off <<= 1) v += __shfl_xor(v, off, 64);
  if (t == 0) out[0] = 0.5f * v / 64.f;
  out[1 + 8192 + t] = (float)t;   // targets = arange(64)
}

extern "C" void kernel_launch(void* const* d_in, const int* in_sizes, int n_in,
                              void* d_out, int out_size, void* d_ws, size_t ws_size,
                              hipStream_t stream) {
  const float* image = (const float*)d_in[0];   // (64,197,768) f32
  const float* text  = (const float*)d_in[1];   // (64,65,768) f32
  const int*   pm    = (const int*)d_in[2];     // (64,65) i32
  const float* ls    = (const float*)d_in[3];   // scalar
  float* out = (float*)d_out;

  _Float16* imgh = (_Float16*)d_ws;                       // 64*196*768 f16
  _Float16* txth = imgh + (size_t)64 * NROW * DIM;        // 64*64*768 f16

  const int total4 = IMG4 + TXT4;   // 3,194,880 -> 12480 blocks
  convert_both<<<(total4 + 255) / 256, 256, 0, stream>>>(image, text, imgh, txth);

  dim3 grid(64, 64);   // x = j (fast) so img[i] stays hot across consecutive blocks
  sim_kernel<<<grid, 256, 0, stream>>>(imgh, txth, pm, ls, out + 1, out + 1 + 4096);
  ce_kernel<<<1, 64, 0, stream>>>(out);
}

// Round 3
// 270.697 us; speedup vs baseline: 1.1241x; 1.1241x over previous
//
#include <hip/hip_runtime.h>

typedef _Float16 half8 __attribute__((ext_vector_type(8)));
typedef float floatx4 __attribute__((ext_vector_type(4)));
typedef float float4v __attribute__((ext_vector_type(4)));

#define DIM   768
#define NROW  196
#define NSTEP 24                      // 768 / 32
#define AUNITS (64 * 13 * 24 * 64)    // 16B units in A'' (fragment-tiled image)
#define TUNITS (64 * 4 * 24 * 64)     // 16B units in B'' (fragment-tiled text)
#define A_HALFS ((size_t)AUNITS * 8)
#define BJ_HALFS (24 * 4 * 64 * 8)    // 49152 halfs per j
#define SMEM_BYTES (98304 + 2048 + 32)

// ---------- repack: f32 -> f16 into MFMA-fragment-tiled layout ----------
// A''[i][tau][s][lane]{8}: lane l holds A_i[n = tau*16+(l&15)][d = s*32+(l>>4)*8 ..+7]
//   (rows clamped at 195: tiles pad 196->208 with dup rows, discarded in epilogue)
// B''[j][s][ct][lane]{8}: lane l holds B_j[m = ct*16+(l&15)][d = s*32+(l>>4)*8 ..+7]
//   (s-major so the first K-half is a contiguous 48 KB block)
__global__ __launch_bounds__(256) void repack(const float* __restrict__ img,
                                              const float* __restrict__ txt,
                                              _Float16* __restrict__ Apk,
                                              _Float16* __restrict__ Bpk) {
  int gid = blockIdx.x * 256 + threadIdx.x;
  const float* src;
  _Float16* dst;
  if (gid < AUNITS) {
    int l = gid & 63, g = gid >> 6;
    int s = g % 24; g /= 24;
    int tau = g % 13; int i = g / 13;
    int n = tau * 16 + (l & 15); if (n > 195) n = 195;
    src = img + (size_t)i * 197 * 768 + (size_t)(n + 1) * 768 + s * 32 + (l >> 4) * 8;
    dst = Apk + (size_t)gid * 8;
  } else {
    int u = gid - AUNITS;
    int l = u & 63, g = u >> 6;
    int ct = g & 3; g >>= 2;
    int s = g % 24; int j = g / 24;
    int m = ct * 16 + (l & 15);
    src = txt + (size_t)j * 65 * 768 + (size_t)(m + 1) * 768 + s * 32 + (l >> 4) * 8;
    dst = Bpk + (size_t)u * 8;
  }
  float4v v0 = *(const float4v*)src;
  float4v v1 = *(const float4v*)(src + 4);
  half8 h;
  h[0] = (_Float16)v0[0]; h[1] = (_Float16)v0[1]; h[2] = (_Float16)v0[2]; h[3] = (_Float16)v0[3];
  h[4] = (_Float16)v1[0]; h[5] = (_Float16)v1[1]; h[6] = (_Float16)v1[2]; h[7] = (_Float16)v1[3];
  *(half8*)dst = h;
}

// ---------- per-(i,j) block: A streamed from global, B staged once in LDS ----------
__global__ __launch_bounds__(512, 2) void sim_kernel(const _Float16* __restrict__ Apk,
                                                     const _Float16* __restrict__ Bpk,
                                                     const int* __restrict__ pm,
                                                     const float* __restrict__ ls,
                                                     float* __restrict__ lpi,
                                                     float* __restrict__ lpt) {
  extern __shared__ _Float16 Bsh[];            // 49152 halfs (96 KB)
  float* colmaxLDS = (float*)(Bsh + 49152);    // [8][64]
  float* wsumLDS = colmaxLDS + 512;            // [8]

  const int j = blockIdx.x, i = blockIdx.y;
  const int tid = threadIdx.x;
  const int wave = tid >> 6, lane = tid & 63;
  const int quad = lane >> 4, r16 = lane & 15;
  const int lane8 = lane * 8;
  const int NT = (wave < 5) ? 2 : 1;           // waves 0-4 own tiles {w, w+8}; 5-7 own {w}
  const int tau0 = wave;
  const int tau1 = (wave + 8 <= 12) ? wave + 8 : wave;

  const _Float16* Ab = Apk + (size_t)i * 13 * 24 * 512;
  const _Float16* pA0 = Ab + (size_t)tau0 * 24 * 512 + lane8;
  const _Float16* pA1 = Ab + (size_t)tau1 * 24 * 512 + lane8;
  const _Float16* Bg = Bpk + (size_t)j * BJ_HALFS;

  // early A prefetch (independent of LDS; in flight during staging)
  half8 afA[2], afB[2], afC[2];
  afA[0] = *(const half8*)(pA0);
  afB[0] = *(const half8*)(pA0 + 512);
  if (NT == 2) {
    afA[1] = *(const half8*)(pA1);
    afB[1] = *(const half8*)(pA1 + 512);
  }

  // stage B: flat identity copy, contiguous 1024 B per wave-instr.
  // region0 = K-steps 0..11 (units 0..3071), region1 = steps 12..23.
  half8 st0[6], st1[6];
#pragma unroll
  for (int r = 0; r < 6; ++r) st0[r] = *(const half8*)(Bg + (tid + 512 * r) * 8);
#pragma unroll
  for (int r = 0; r < 6; ++r) st1[r] = *(const half8*)(Bg + (3072 + tid + 512 * r) * 8);
#pragma unroll
  for (int r = 0; r < 6; ++r) *(half8*)(Bsh + (tid + 512 * r) * 8) = st0[r];
  __syncthreads();                              // region0 visible (drains all vmcnt)
#pragma unroll
  for (int r = 0; r < 6; ++r) *(half8*)(Bsh + (3072 + tid + 512 * r) * 8) = st1[r];

  floatx4 acc[2][4];
#pragma unroll
  for (int t = 0; t < 2; ++t)
#pragma unroll
    for (int ct = 0; ct < 4; ++ct)
      acc[t][ct] = (floatx4){0.f, 0.f, 0.f, 0.f};

  // ---- phase 1: K-steps 0..11 (reads Bsh region0 only) ----
#pragma unroll
  for (int s = 0; s < 12; ++s) {
    afC[0] = *(const half8*)(pA0 + (s + 2) * 512);
    if (NT == 2) afC[1] = *(const half8*)(pA1 + (s + 2) * 512);
    half8 bfr[4];
#pragma unroll
    for (int ct = 0; ct < 4; ++ct)
      bfr[ct] = *(const half8*)(Bsh + (s * 4 + ct) * 512 + lane8);
#pragma unroll
    for (int t = 0; t < 2; ++t)
      if (t < NT)
#pragma unroll
        for (int ct = 0; ct < 4; ++ct)
          acc[t][ct] = __builtin_amdgcn_mfma_f32_16x16x32_f16(afA[t], bfr[ct], acc[t][ct], 0, 0, 0);
    afA[0] = afB[0]; afA[1] = afB[1];
    afB[0] = afC[0]; afB[1] = afC[1];
  }
  __syncthreads();                              // region1 ds_writes visible

  // ---- phase 2: K-steps 12..23 ----
#pragma unroll
  for (int s = 12; s < 24; ++s) {
    if (s < 22) {
      afC[0] = *(const half8*)(pA0 + (s + 2) * 512);
      if (NT == 2) afC[1] = *(const half8*)(pA1 + (s + 2) * 512);
    }
    half8 bfr[4];
#pragma unroll
    for (int ct = 0; ct < 4; ++ct)
      bfr[ct] = *(const half8*)(Bsh + (s * 4 + ct) * 512 + lane8);
#pragma unroll
    for (int t = 0; t < 2; ++t)
      if (t < NT)
#pragma unroll
        for (int ct = 0; ct < 4; ++ct)
          acc[t][ct] = __builtin_amdgcn_mfma_f32_16x16x32_f16(afA[t], bfr[ct], acc[t][ct], 0, 0, 0);
    afA[0] = afB[0]; afA[1] = afB[1];
    afB[0] = afC[0]; afB[1] = afC[1];
  }

  // ---------------- epilogue ----------------
  const float sgl = ls[0];
  // reference broadcasts pm over i (NOT j): col m masked iff pm[i, m+1] != 0
  bool maskc[4];
#pragma unroll
  for (int ct = 0; ct < 4; ++ct)
    maskc[ct] = pm[i * 65 + 1 + ct * 16 + r16] != 0;

  // logits_per_image: mean_n of max over valid m
  float rowsum = 0.f;
#pragma unroll
  for (int t = 0; t < 2; ++t) {
    if (t < NT) {
      int taut = t ? tau1 : tau0;
#pragma unroll
      for (int r = 0; r < 4; ++r) {
        int row = taut * 16 + quad * 4 + r;     // C/D: row = quad*4 + reg
        float rm = -__builtin_inff();
#pragma unroll
        for (int ct = 0; ct < 4; ++ct) {
          float v = acc[t][ct][r] * sgl;
          rm = fmaxf(rm, maskc[ct] ? -__builtin_inff() : v);
        }
#pragma unroll
        for (int off = 1; off < 16; off <<= 1)
          rm = fmaxf(rm, __shfl_xor(rm, off, 64));
        if (row < NROW) rowsum += rm;           // counted by all 16 r16 lanes
      }
    }
  }
#pragma unroll
  for (int off = 1; off < 64; off <<= 1) rowsum += __shfl_xor(rowsum, off, 64);
  if (lane == 0) wsumLDS[wave] = rowsum;

  // logits_per_text: masked mean over m of max over n (pad rows excluded)
  float cm[4];
#pragma unroll
  for (int ct = 0; ct < 4; ++ct) {
    cm[ct] = -__builtin_inff();
#pragma unroll
    for (int t = 0; t < 2; ++t) {
      if (t < NT) {
        int taut = t ? tau1 : tau0;
#pragma unroll
        for (int r = 0; r < 4; ++r) {
          int row = taut * 16 + quad * 4 + r;
          if (row < NROW) cm[ct] = fmaxf(cm[ct], acc[t][ct][r] * sgl);
        }
      }
    }
    cm[ct] = fmaxf(cm[ct], __shfl_xor(cm[ct], 16, 64));
    cm[ct] = fmaxf(cm[ct], __shfl_xor(cm[ct], 32, 64));
  }
  if (lane < 16) {
#pragma unroll
    for (int ct = 0; ct < 4; ++ct) colmaxLDS[wave * 64 + ct * 16 + lane] = cm[ct];
  }
  __syncthreads();

  if (tid == 0) {
    float total = 0.f;
#pragma unroll
    for (int w = 0; w < 8; ++w) total += wsumLDS[w];
    lpi[i * 64 + j] = total / (16.f * (float)NROW);
  }
  if (tid < 64) {   // exactly wave 0
    float v = -__builtin_inff();
#pragma unroll
    for (int w = 0; w < 8; ++w) v = fmaxf(v, colmaxLDS[w * 64 + tid]);
    bool valid = pm[i * 65 + 1 + tid] == 0;
    float contrib = valid ? v : 0.f;
    float cntv = valid ? 1.f : 0.f;
#pragma unroll
    for (int off = 1; off < 64; off <<= 1) {
      contrib += __shfl_xor(contrib, off, 64);
      cntv += __shfl_xor(cntv, off, 64);
    }
    if (tid == 0) lpt[i * 64 + j] = contrib / cntv;
  }
}

// ---------------- CE losses + targets ----------------
// out layout: [0] loss | [1..4097) lpi | [4097..8193) lpt | [8193..8257) targets
__global__ __launch_bounds__(64) void ce_kernel(float* __restrict__ out) {
  const int t = threadIdx.x;  // 1 wave, thread t = row t
  const float* lpi = out + 1;
  const float* lpt = out + 1 + 4096;

  float mx = -__builtin_inff();
  for (int jj = 0; jj < 64; ++jj) mx = fmaxf(mx, lpi[t * 64 + jj]);
  float se = 0.f;
  for (int jj = 0; jj < 64; ++jj) se += __expf(lpi[t * 64 + jj] - mx);
  float ci = (mx + __logf(se)) - lpi[t * 64 + t];

  float mx2 = -__builtin_inff();
  for (int jj = 0; jj < 64; ++jj) mx2 = fmaxf(mx2, lpt[t * 64 + jj]);
  float se2 = 0.f;
  for (int jj = 0; jj < 64; ++jj) se2 += __expf(lpt[t * 64 + jj] - mx2);
  float ct_ = (mx2 + __logf(se2)) - lpt[t * 64 + t];

  float v = ci + ct_;
#pragma unroll
  for (int off = 1; off < 64; off <<= 1) v += __shfl_xor(v, off, 64);
  if (t == 0) out[0] = 0.5f * v / 64.f;
  out[1 + 8192 + t] = (float)t;   // targets = arange(64)
}

extern "C" void kernel_launch(void* const* d_in, const int* in_sizes, int n_in,
                              void* d_out, int out_size, void* d_ws, size_t ws_size,
                              hipStream_t stream) {
  const float* image = (const float*)d_in[0];   // (64,197,768) f32
  const float* text  = (const float*)d_in[1];   // (64,65,768) f32
  const int*   pm    = (const int*)d_in[2];     // (64,65) i32
  const float* ls    = (const float*)d_in[3];   // scalar
  float* out = (float*)d_out;

  _Float16* Apk = (_Float16*)d_ws;              // 20.4 MB fragment-tiled image
  _Float16* Bpk = Apk + A_HALFS;                // 6.3 MB fragment-tiled text

  hipFuncSetAttribute(reinterpret_cast<const void*>(sim_kernel),
                      hipFuncAttributeMaxDynamicSharedMemorySize, SMEM_BYTES);

  repack<<<(AUNITS + TUNITS) / 256, 256, 0, stream>>>(image, text, Apk, Bpk);

  dim3 grid(64, 64);   // x = j (fast) so A_i stays L2-hot across consecutive blocks
  sim_kernel<<<grid, 512, SMEM_BYTES, stream>>>(Apk, Bpk, pm, ls, out + 1, out + 1 + 4096);
  ce_kernel<<<1, 64, 0, stream>>>(out);
}

// Round 4
// 203.137 us; speedup vs baseline: 1.4980x; 1.3326x over previous
//
#include <hip/hip_runtime.h>

typedef _Float16 half8 __attribute__((ext_vector_type(8)));
typedef float floatx4 __attribute__((ext_vector_type(4)));
typedef float float4v __attribute__((ext_vector_type(4)));

#define DIM   768
#define NROW  196
#define AUNITS (64 * 13 * 24 * 64)    // 16B units in A'' (fragment-tiled image)
#define TUNITS (64 * 4 * 24 * 64)     // 16B units in B'' (fragment-tiled text)
#define A_HALFS ((size_t)AUNITS * 8)
#define BJ_HALFS (24 * 4 * 64 * 8)    // 49152 halfs per j

__device__ __forceinline__ void gl_lds16(const _Float16* g, _Float16* l) {
  __builtin_amdgcn_global_load_lds(
      (const __attribute__((address_space(1))) unsigned int*)g,
      (__attribute__((address_space(3))) unsigned int*)l, 16, 0, 0);
}

// ---------- repack: f32 -> f16 into MFMA-fragment-tiled layout ----------
// A''[i][tau][s][lane]{8}: lane l holds A_i[n=tau*16+(l&15)][d=s*32+(l>>4)*8..+7]
// B''[j][s][ct][lane]{8}:  lane l holds B_j[m=ct*16+(l&15)][d=s*32+(l>>4)*8..+7]
__global__ __launch_bounds__(256) void repack(const float* __restrict__ img,
                                              const float* __restrict__ txt,
                                              _Float16* __restrict__ Apk,
                                              _Float16* __restrict__ Bpk) {
  int gid = blockIdx.x * 256 + threadIdx.x;
  const float* src;
  _Float16* dst;
  if (gid < AUNITS) {
    int l = gid & 63, g = gid >> 6;
    int s = g % 24; g /= 24;
    int tau = g % 13; int i = g / 13;
    int n = tau * 16 + (l & 15); if (n > 195) n = 195;   // dup-pad rows 196..207
    src = img + (size_t)i * 197 * 768 + (size_t)(n + 1) * 768 + s * 32 + (l >> 4) * 8;
    dst = Apk + (size_t)gid * 8;
  } else {
    int u = gid - AUNITS;
    int l = u & 63, g = u >> 6;
    int ct = g & 3; g >>= 2;
    int s = g % 24; int j = g / 24;
    int m = ct * 16 + (l & 15);
    src = txt + (size_t)j * 65 * 768 + (size_t)(m + 1) * 768 + s * 32 + (l >> 4) * 8;
    dst = Bpk + (size_t)u * 8;
  }
  float4v v0 = *(const float4v*)src;
  float4v v1 = *(const float4v*)(src + 4);
  half8 h;
  h[0] = (_Float16)v0[0]; h[1] = (_Float16)v0[1]; h[2] = (_Float16)v0[2]; h[3] = (_Float16)v0[3];
  h[4] = (_Float16)v1[0]; h[5] = (_Float16)v1[1]; h[6] = (_Float16)v1[2]; h[7] = (_Float16)v1[3];
  *(half8*)dst = h;
}

// ---------- per-(i,j): A streamed via registers, B half-K staged by DMA ----------
// 4 waves; wave w owns row tiles {w, w+4, w+8} (rows 0..191) fully, plus
// column-group w of tile 12 (rows 192..195; 196..207 dup-pad discarded).
__global__ __launch_bounds__(256, 3) void sim_kernel(const _Float16* __restrict__ Apk,
                                                     const _Float16* __restrict__ Bpk,
                                                     const int* __restrict__ pm,
                                                     const float* __restrict__ ls,
                                                     float* __restrict__ lpi,
                                                     float* __restrict__ lpt) {
  __shared__ _Float16 Bsh[24576];           // 48 KB: one K-half of B_j
  __shared__ float colmaxLDS[4][64];
  __shared__ float t12buf[4][64];
  __shared__ float wsumLDS[4];

  const int j = blockIdx.x, i = blockIdx.y;
  const int tid = threadIdx.x;
  const int wave = tid >> 6, lane = tid & 63;
  const int r16 = lane & 15;
  const int lane8 = lane * 8;

  const _Float16* Ai = Apk + (size_t)i * 13 * 24 * 512;
  const _Float16* pA[4];
  pA[0] = Ai + (size_t)(wave)     * 24 * 512 + lane8;
  pA[1] = Ai + (size_t)(wave + 4) * 24 * 512 + lane8;
  pA[2] = Ai + (size_t)(wave + 8) * 24 * 512 + lane8;
  pA[3] = Ai + (size_t)12         * 24 * 512 + lane8;   // tile 12 (all waves)
  const _Float16* Bg = Bpk + (size_t)j * BJ_HALFS;

  // A pipeline, depth 2 K-steps x 4 fragments
  half8 af[2][4];
#pragma unroll
  for (int t = 0; t < 4; ++t) {
    af[0][t] = *(const half8*)(pA[t]);
    af[1][t] = *(const half8*)(pA[t] + 512);
  }

  floatx4 acc[3][4];
  floatx4 acc12 = (floatx4){0.f, 0.f, 0.f, 0.f};
#pragma unroll
  for (int t = 0; t < 3; ++t)
#pragma unroll
    for (int cc = 0; cc < 4; ++cc)
      acc[t][cc] = (floatx4){0.f, 0.f, 0.f, 0.f};

  for (int h = 0; h < 2; ++h) {
    __syncthreads();                        // previous half fully consumed
    // stage 48 KB: 48 x 1024B contiguous DMA instrs, 12 per wave
#pragma unroll
    for (int r = 0; r < 12; ++r) {
      int u = wave * 12 + r;
      gl_lds16(Bg + h * 24576 + u * 512 + lane8, Bsh + u * 512);
    }
    __syncthreads();                        // DMA drained -> data visible

#pragma unroll
    for (int sc = 0; sc < 12; ++sc) {
      half8 bfr[4];
#pragma unroll
      for (int cc = 0; cc < 4; ++cc) {
        int ct = (wave + cc) & 3;           // rotated: bfr[0] is this wave's own group
        bfr[cc] = *(const half8*)(Bsh + (sc * 4 + ct) * 512 + lane8);
      }
      half8 a0 = af[sc & 1][0], a1 = af[sc & 1][1], a2 = af[sc & 1][2], a3 = af[sc & 1][3];
      if (h == 0 || sc < 10) {              // prefetch K-step s+2
        int s2 = h * 12 + sc + 2;
#pragma unroll
        for (int t = 0; t < 4; ++t) af[sc & 1][t] = *(const half8*)(pA[t] + s2 * 512);
      }
#pragma unroll
      for (int cc = 0; cc < 4; ++cc) {
        acc[0][cc] = __builtin_amdgcn_mfma_f32_16x16x32_f16(a0, bfr[cc], acc[0][cc], 0, 0, 0);
        acc[1][cc] = __builtin_amdgcn_mfma_f32_16x16x32_f16(a1, bfr[cc], acc[1][cc], 0, 0, 0);
        acc[2][cc] = __builtin_amdgcn_mfma_f32_16x16x32_f16(a2, bfr[cc], acc[2][cc], 0, 0, 0);
      }
      acc12 = __builtin_amdgcn_mfma_f32_16x16x32_f16(a3, bfr[0], acc12, 0, 0, 0);
    }
  }

  // ---------------- epilogue ----------------
  const float sgl = ls[0];
  // mask depends on i only (reference broadcasts pm over i, not j)
  bool msk[4];
  int colc[4];
#pragma unroll
  for (int cc = 0; cc < 4; ++cc) {
    colc[cc] = ((wave + cc) & 3) * 16 + r16;
    msk[cc] = pm[i * 65 + 1 + colc[cc]] != 0;
  }

  // logits_per_image part 1: rows 0..191 (each row counted by 16 r16-lanes)
  float rowsum = 0.f;
#pragma unroll
  for (int t = 0; t < 3; ++t) {
#pragma unroll
    for (int r = 0; r < 4; ++r) {
      float rm = -__builtin_inff();
#pragma unroll
      for (int cc = 0; cc < 4; ++cc) {
        float v = acc[t][cc][r] * sgl;
        rm = fmaxf(rm, msk[cc] ? -__builtin_inff() : v);
      }
#pragma unroll
      for (int off = 1; off < 16; off <<= 1)
        rm = fmaxf(rm, __shfl_xor(rm, off, 64));
      rowsum += rm;
    }
  }
#pragma unroll
  for (int off = 1; off < 64; off <<= 1) rowsum += __shfl_xor(rowsum, off, 64);
  if (lane == 0) wsumLDS[wave] = rowsum;

  // colmax over rows 0..191 (unmasked per reference max_n)
#pragma unroll
  for (int cc = 0; cc < 4; ++cc) {
    float cm = -__builtin_inff();
#pragma unroll
    for (int t = 0; t < 3; ++t)
#pragma unroll
      for (int r = 0; r < 4; ++r)
        cm = fmaxf(cm, acc[t][cc][r] * sgl);
    cm = fmaxf(cm, __shfl_xor(cm, 16, 64));
    cm = fmaxf(cm, __shfl_xor(cm, 32, 64));
    if (lane < 16) colmaxLDS[wave][colc[cc]] = cm;
  }
  // tile-12 rows 192..195 (quad==0 regs), this wave's own column group
  if (lane < 16) {
#pragma unroll
    for (int r = 0; r < 4; ++r) t12buf[r][wave * 16 + r16] = acc12[r] * sgl;
  }
  __syncthreads();

  if (tid < 64) {   // wave 0
    int col = tid;
    bool valid = pm[i * 65 + 1 + col] == 0;
    float t0 = t12buf[0][col], t1 = t12buf[1][col], t2 = t12buf[2][col], t3 = t12buf[3][col];
    float v = fmaxf(fmaxf(colmaxLDS[0][col], colmaxLDS[1][col]),
                    fmaxf(colmaxLDS[2][col], colmaxLDS[3][col]));
    v = fmaxf(v, fmaxf(fmaxf(t0, t1), fmaxf(t2, t3)));       // full col max (n=0..195)
    float contrib = valid ? v : 0.f;
    float cntv = valid ? 1.f : 0.f;
    float rs0 = valid ? t0 : -__builtin_inff();
    float rs1 = valid ? t1 : -__builtin_inff();
    float rs2 = valid ? t2 : -__builtin_inff();
    float rs3 = valid ? t3 : -__builtin_inff();
#pragma unroll
    for (int off = 1; off < 64; off <<= 1) {
      contrib += __shfl_xor(contrib, off, 64);
      cntv += __shfl_xor(cntv, off, 64);
      rs0 = fmaxf(rs0, __shfl_xor(rs0, off, 64));
      rs1 = fmaxf(rs1, __shfl_xor(rs1, off, 64));
      rs2 = fmaxf(rs2, __shfl_xor(rs2, off, 64));
      rs3 = fmaxf(rs3, __shfl_xor(rs3, off, 64));
    }
    if (tid == 0) {
      lpt[i * 64 + j] = contrib / cntv;
      float total = (wsumLDS[0] + wsumLDS[1] + wsumLDS[2] + wsumLDS[3]) * 0.0625f
                  + rs0 + rs1 + rs2 + rs3;
      lpi[i * 64 + j] = total / 196.f;
    }
  }
}

// ---------------- CE losses + targets ----------------
// out layout: [0] loss | [1..4097) lpi | [4097..8193) lpt | [8193..8257) targets
__global__ __launch_bounds__(64) void ce_kernel(float* __restrict__ out) {
  const int t = threadIdx.x;
  const float* lpi = out + 1;
  const float* lpt = out + 1 + 4096;

  float mx = -__builtin_inff();
  for (int jj = 0; jj < 64; ++jj) mx = fmaxf(mx, lpi[t * 64 + jj]);
  float se = 0.f;
  for (int jj = 0; jj < 64; ++jj) se += __expf(lpi[t * 64 + jj] - mx);
  float ci = (mx + __logf(se)) - lpi[t * 64 + t];

  float mx2 = -__builtin_inff();
  for (int jj = 0; jj < 64; ++jj) mx2 = fmaxf(mx2, lpt[t * 64 + jj]);
  float se2 = 0.f;
  for (int jj = 0; jj < 64; ++jj) se2 += __expf(lpt[t * 64 + jj] - mx2);
  float ct_ = (mx2 + __logf(se2)) - lpt[t * 64 + t];

  float v = ci + ct_;
#pragma unroll
  for (int off = 1; off < 64; off <<= 1) v += __shfl_xor(v, off, 64);
  if (t == 0) out[0] = 0.5f * v / 64.f;
  out[1 + 8192 + t] = (float)t;   // targets = arange(64)
}

extern "C" void kernel_launch(void* const* d_in, const int* in_sizes, int n_in,
                              void* d_out, int out_size, void* d_ws, size_t ws_size,
                              hipStream_t stream) {
  const float* image = (const float*)d_in[0];   // (64,197,768) f32
  const float* text  = (const float*)d_in[1];   // (64,65,768) f32
  const int*   pm    = (const int*)d_in[2];     // (64,65) i32
  const float* ls    = (const float*)d_in[3];   // scalar
  float* out = (float*)d_out;

  _Float16* Apk = (_Float16*)d_ws;              // fragment-tiled image
  _Float16* Bpk = Apk + A_HALFS;                // fragment-tiled text

  repack<<<(AUNITS + TUNITS) / 256, 256, 0, stream>>>(image, text, Apk, Bpk);

  dim3 grid(64, 64);   // x = j (fast): A_i reused by consecutive blocks
  sim_kernel<<<grid, 256, 0, stream>>>(Apk, Bpk, pm, ls, out + 1, out + 1 + 4096);
  ce_kernel<<<1, 64, 0, stream>>>(out);
}